// Round 5
// baseline (143.348 us; speedup 1.0000x reference)
//
#include <hip/hip_runtime.h>
#include <math.h>

#define NG   512
#define NPER 256
#define DD   128
#define EPER 4096
#define KK   128
#define NN   (NG * NPER)   // 131072 nodes

// ---------------- K1: xw[n] = dot(x[n,:], gcn_w) ----------------
// 64 rows per 256-thread block, grid = NN/64 = 2048.
// Per lane: 8 independent float4 x-loads + 8 float4 w-loads -> deep ILP.
__global__ __launch_bounds__(256, 4) void k_xw(
    const float* __restrict__ x, const float* __restrict__ gcn_w,
    float* __restrict__ xw)
{
  const int tid  = threadIdx.x;
  const int lane = tid & 63;
  const int wave = tid >> 6;
  const int r    = lane >> 2;          // 16 rows per wave
  const int q    = lane & 3;           // 4 lanes per row
  const int node = blockIdx.x * 64 + wave * 16 + r;

  const float4* x4 = (const float4*)x;
  const float4* w4 = (const float4*)gcn_w;

  float4 wv[8], qv[8];
  #pragma unroll
  for (int i = 0; i < 8; ++i) wv[i] = w4[i * 4 + q];           // L2-broadcast
  #pragma unroll
  for (int i = 0; i < 8; ++i) qv[i] = x4[node * 32 + i * 4 + q]; // 8 loads in flight

  float acc = 0.f;
  #pragma unroll
  for (int i = 0; i < 8; ++i)
    acc += qv[i].x * wv[i].x + qv[i].y * wv[i].y
         + qv[i].z * wv[i].z + qv[i].w * wv[i].w;
  acc += __shfl_xor(acc, 1);           // reduce across the 4 q-lanes (DPP)
  acc += __shfl_xor(acc, 2);
  if (q == 0) xw[node] = acc;
}

// ---------------- K2: per-graph deg -> score -> top-K -> gate ----------------
// grid = 512 (1 block/graph), 512 threads.
__global__ __launch_bounds__(512, 4) void k_score(
    const float* __restrict__ xw,
    const int*   __restrict__ esrc, const int* __restrict__ edst,
    const float* __restrict__ gcn_b,
    float2* __restrict__ gateflag)      // [N]: (gate, keep?1:0)
{
  const int g   = blockIdx.x;
  const int tid = threadIdx.x;

  __shared__ int    sDeg[NPER];
  __shared__ int    sRank[NPER];
  __shared__ float  sXWn[NPER];
  __shared__ float  sDinv[NPER];
  __shared__ float4 sScore4[NPER / 4];
  float* sScore = (float*)sScore4;

  // prefetch 8 edges/thread + this node's xw before first barrier
  const int4* es4 = (const int4*)(esrc + (size_t)g * EPER);
  const int4* ed4 = (const int4*)(edst + (size_t)g * EPER);
  int4 sa = es4[tid], sb = es4[512 + tid];
  int4 da = ed4[tid], db = ed4[512 + tid];
  float xwv = (tid < NPER) ? xw[(size_t)g * NPER + tid] : 0.f;

  if (tid < NPER) { sDeg[tid] = 1; sRank[tid] = 0; }
  __syncthreads();

  atomicAdd(&sDeg[da.x & 255], 1);
  atomicAdd(&sDeg[da.y & 255], 1);
  atomicAdd(&sDeg[da.z & 255], 1);
  atomicAdd(&sDeg[da.w & 255], 1);
  atomicAdd(&sDeg[db.x & 255], 1);
  atomicAdd(&sDeg[db.y & 255], 1);
  atomicAdd(&sDeg[db.z & 255], 1);
  atomicAdd(&sDeg[db.w & 255], 1);
  __syncthreads();

  if (tid < NPER) {
    float dv = 1.0f / sqrtf((float)sDeg[tid]);
    sDinv[tid]  = dv;
    sXWn[tid]   = xwv * dv;
    sScore[tid] = xwv * dv * dv;       // self-loop term
  }
  __syncthreads();

  {
    int s0 = sa.x & 255, d0 = da.x & 255;
    int s1 = sa.y & 255, d1 = da.y & 255;
    int s2 = sa.z & 255, d2 = da.z & 255;
    int s3 = sa.w & 255, d3 = da.w & 255;
    int s4 = sb.x & 255, d4 = db.x & 255;
    int s5 = sb.y & 255, d5 = db.y & 255;
    int s6 = sb.z & 255, d6 = db.z & 255;
    int s7 = sb.w & 255, d7 = db.w & 255;
    atomicAdd(&sScore[d0], sXWn[s0] * sDinv[d0]);
    atomicAdd(&sScore[d1], sXWn[s1] * sDinv[d1]);
    atomicAdd(&sScore[d2], sXWn[s2] * sDinv[d2]);
    atomicAdd(&sScore[d3], sXWn[s3] * sDinv[d3]);
    atomicAdd(&sScore[d4], sXWn[s4] * sDinv[d4]);
    atomicAdd(&sScore[d5], sXWn[s5] * sDinv[d5]);
    atomicAdd(&sScore[d6], sXWn[s6] * sDinv[d6]);
    atomicAdd(&sScore[d7], sXWn[s7] * sDinv[d7]);
  }
  __syncthreads();

  // stable top-K rank: 2 threads/node, b128 broadcast reads
  {
    int node = tid & 255;
    int seg  = tid >> 8;               // 0/1 -> j in [seg*128, seg*128+128)
    float s_i = sScore[node];
    int base = seg * 32;
    int part = 0;
    #pragma unroll 8
    for (int t = 0; t < 32; ++t) {
      float4 v = sScore4[base + t];
      int jj = (base + t) * 4;
      part += (v.x > s_i) || (v.x == s_i && (jj + 0) < node);
      part += (v.y > s_i) || (v.y == s_i && (jj + 1) < node);
      part += (v.z > s_i) || (v.z == s_i && (jj + 2) < node);
      part += (v.w > s_i) || (v.w == s_i && (jj + 3) < node);
    }
    atomicAdd(&sRank[node], part);
  }
  __syncthreads();

  if (tid < NPER) {
    int rk = sRank[tid];               // ranks are a permutation of 0..255
    float2 gf = (rk < KK)
        ? make_float2(tanhf(sScore[tid] + gcn_b[0]), 1.0f)
        : make_float2(0.f, 0.f);
    gateflag[(size_t)g * NPER + tid] = gf;
  }
}

// ---------------- K3: gated mean/max pool + out = [mean||max]@lin_w + b ----------------
// grid = 512 (1 block/graph), 512 threads = 8 waves; wave w streams nodes [w*32, w*32+32).
__global__ __launch_bounds__(512, 4) void k_pool(
    const float*  __restrict__ x,
    const float2* __restrict__ gateflag,
    const float*  __restrict__ lin_w, const float* __restrict__ lin_b,
    float* __restrict__ out)
{
  const int g    = blockIdx.x;
  const int tid  = threadIdx.x;
  const int lane = tid & 63;
  const int wave = tid >> 6;

  __shared__ float2 sGF[NPER];
  __shared__ float2 sPS[8][64];
  __shared__ float2 sPM[8][64];
  __shared__ float2 sR2[DD];           // [0..63] mean pairs, [64..127] max pairs

  if (tid < NPER) sGF[tid] = gateflag[(size_t)g * NPER + tid];
  __syncthreads();

  const float2* xg2 = (const float2*)(x + (size_t)g * NPER * DD);
  float sm0 = 0.f, sm1 = 0.f, mx0 = -INFINITY, mx1 = -INFINITY;
  #pragma unroll
  for (int nn = 0; nn < 32; ++nn) {
    int node = wave * 32 + nn;
    float2 gf = sGF[node];             // b64 broadcast
    float2 p  = xg2[node * 64 + lane]; // 512 B contiguous per wave-instr
    bool kp = (gf.y != 0.f);
    float a = p.x * gf.x, b = p.y * gf.x;   // gate=0 for dropped -> sum ok
    sm0 += a; sm1 += b;
    mx0 = fmaxf(mx0, kp ? a : -INFINITY);
    mx1 = fmaxf(mx1, kp ? b : -INFINITY);
  }
  sPS[wave][lane] = make_float2(sm0, sm1);
  sPM[wave][lane] = make_float2(mx0, mx1);
  __syncthreads();

  if (wave == 0) {
    float2 a = sPS[0][lane];
    #pragma unroll
    for (int w = 1; w < 8; ++w) { float2 p = sPS[w][lane]; a.x += p.x; a.y += p.y; }
    sR2[lane] = make_float2(a.x * (1.0f / KK), a.y * (1.0f / KK));
  } else if (wave == 1) {
    float2 a = sPM[0][lane];
    #pragma unroll
    for (int w = 1; w < 8; ++w) {
      float2 p = sPM[w][lane];
      a.x = fmaxf(a.x, p.x); a.y = fmaxf(a.y, p.y);
    }
    sR2[64 + lane] = a;
  }
  __syncthreads();

  // matvec: wave w handles readout float2-chunks k2 in [w*16, w*16+16)
  const float2* lw2 = (const float2*)lin_w;
  float a0 = 0.f, a1 = 0.f;
  #pragma unroll
  for (int t = 0; t < 16; ++t) {
    int k2 = wave * 16 + t;
    float2 rv = sR2[k2];                       // readout[2k2], readout[2k2+1]
    float2 p0 = lw2[(2 * k2) * 64 + lane];     // L2-hot across blocks
    float2 p1 = lw2[(2 * k2 + 1) * 64 + lane];
    a0 += rv.x * p0.x + rv.y * p1.x;
    a1 += rv.x * p0.y + rv.y * p1.y;
  }
  sPS[wave][lane] = make_float2(a0, a1);       // safe: all passed last barrier
  __syncthreads();
  if (wave == 0) {
    float2 a = sPS[0][lane];
    #pragma unroll
    for (int w = 1; w < 8; ++w) { float2 p = sPS[w][lane]; a.x += p.x; a.y += p.y; }
    float2 bb = ((const float2*)lin_b)[lane];
    a.x += bb.x; a.y += bb.y;
    ((float2*)out)[(size_t)g * 64 + lane] = a;
  }
}

extern "C" void kernel_launch(void* const* d_in, const int* in_sizes, int n_in,
                              void* d_out, int out_size, void* d_ws, size_t ws_size,
                              hipStream_t stream) {
  const float* x  = (const float*)d_in[0];
  // d_in[1] = graph_indicator (unused: equal-size contiguous graphs)
  const int*   ei = (const int*)d_in[2];
  const float* gw = (const float*)d_in[3];
  const float* gb = (const float*)d_in[4];
  const float* lw = (const float*)d_in[5];
  const float* lb = (const float*)d_in[6];
  float* out = (float*)d_out;
  const int E = in_sizes[2] / 2;       // edge_index is [2, E]

  float*  xw = (float*)d_ws;                            // [N] floats (512 KB)
  float2* gf = (float2*)((char*)d_ws + (size_t)NN * 4); // [N] float2 (1 MB)

  k_xw   <<<NN / 64, 256, 0, stream>>>(x, gw, xw);
  k_score<<<NG, 512, 0, stream>>>(xw, ei, ei + E, gb, gf);
  k_pool <<<NG, 512, 0, stream>>>(x, gf, lw, lb, out);
}

// Round 6
// 127.725 us; speedup vs baseline: 1.1223x; 1.1223x over previous
//
#include <hip/hip_runtime.h>
#include <math.h>

#define NG   512
#define NPER 256
#define DD   128
#define EPER 4096
#define KK   128
#define NT   512
#define NW   8      // waves per block

__global__ __launch_bounds__(NT, 4) void sag_fused(
    const float* __restrict__ x,      // [N, 128] f32
    const int*   __restrict__ esrc,   // [E]
    const int*   __restrict__ edst,   // [E]
    const float* __restrict__ gcn_w,  // [128]
    const float* __restrict__ gcn_b,  // [1]
    const float* __restrict__ lin_w,  // [256, 128]
    const float* __restrict__ lin_b,  // [128]
    float* __restrict__ out)          // [512, 128]
{
  const int g    = blockIdx.x;
  const int tid  = threadIdx.x;
  const int lane = tid & 63;
  const int wave = tid >> 6;
  const int j    = lane & 15;          // dim-group within 16-lane group
  const int sub  = lane >> 4;          // 0..3

  __shared__ int    sDeg[NPER];
  __shared__ int    sRank[NPER];
  __shared__ float  sXWn[NPER];        // raw xw, then xw*dinv after B2
  __shared__ float  sDinv[NPER];
  __shared__ float4 sScore4[NPER / 4];
  __shared__ float2 sGF[NPER];         // (gate_or_0, 0_or_inf)
  __shared__ float  sPoolS[NW][DD];    // per-wave pool partials (reused for matvec)
  __shared__ float  sPoolM[NW][DD];
  __shared__ float2 sR2[DD];           // readout: [0..127]=mean, [128..255]=max (as pairs)
  float* sScore = (float*)sScore4;
  float* sR     = (float*)sR2;

  // ---- Front-load ALL global reads: 4 int4 edges + 16 float4 x + 2 float4 w
  const int4* es4 = (const int4*)(esrc + (size_t)g * EPER);
  const int4* ed4 = (const int4*)(edst + (size_t)g * EPER);
  int4 sa = es4[tid], sb = es4[NT + tid];
  int4 da = ed4[tid], db = ed4[NT + tid];

  const float4* xg4 = (const float4*)(x + (size_t)g * NPER * DD);
  const int colbase = (wave * 4 + sub) * 32 + j;   // per-thread x base (float4 units)
  float4 q0[8], q1[8];
  #pragma unroll
  for (int r = 0; r < 8; ++r) {
    q0[r] = xg4[r * 1024 + colbase];          // node r*32+wave*4+sub, dims [4j,4j+4)
    q1[r] = xg4[r * 1024 + colbase + 16];     // dims [64+4j, 64+4j+4)
  }
  float4 wa = ((const float4*)gcn_w)[j];
  float4 wb = ((const float4*)gcn_w)[16 + j];

  if (tid < NPER) { sDeg[tid] = 1; sRank[tid] = 0; }
  __syncthreads();                                      // B1

  // ---- Degree (needs only edges)
  atomicAdd(&sDeg[da.x & 255], 1);
  atomicAdd(&sDeg[da.y & 255], 1);
  atomicAdd(&sDeg[da.z & 255], 1);
  atomicAdd(&sDeg[da.w & 255], 1);
  atomicAdd(&sDeg[db.x & 255], 1);
  atomicAdd(&sDeg[db.y & 255], 1);
  atomicAdd(&sDeg[db.z & 255], 1);
  atomicAdd(&sDeg[db.w & 255], 1);

  // ---- P1: xw dot from registers (independent of degree)
  #pragma unroll
  for (int r = 0; r < 8; ++r) {
    float acc = q0[r].x*wa.x + q0[r].y*wa.y + q0[r].z*wa.z + q0[r].w*wa.w
              + q1[r].x*wb.x + q1[r].y*wb.y + q1[r].z*wb.z + q1[r].w*wb.w;
    acc += __shfl_xor(acc, 1);          // DPP within 16-lane group
    acc += __shfl_xor(acc, 2);
    acc += __shfl_xor(acc, 4);
    acc += __shfl_xor(acc, 8);
    if (j == 0) sXWn[r * 32 + wave * 4 + sub] = acc;    // raw xw
  }
  __syncthreads();                                      // B2

  if (tid < NPER) {
    float dv = 1.0f / sqrtf((float)sDeg[tid]);
    float xw = sXWn[tid];
    sDinv[tid]  = dv;
    sXWn[tid]   = xw * dv;              // pre-scaled (same-thread overwrite: safe)
    sScore[tid] = xw * dv * dv;         // self-loop term
  }
  __syncthreads();                                      // B3

  // ---- P3: score[dst] += xwn[src] * dinv[dst]
  {
    int s0 = sa.x & 255, d0 = da.x & 255;
    int s1 = sa.y & 255, d1 = da.y & 255;
    int s2 = sa.z & 255, d2 = da.z & 255;
    int s3 = sa.w & 255, d3 = da.w & 255;
    int s4 = sb.x & 255, d4 = db.x & 255;
    int s5 = sb.y & 255, d5 = db.y & 255;
    int s6 = sb.z & 255, d6 = db.z & 255;
    int s7 = sb.w & 255, d7 = db.w & 255;
    atomicAdd(&sScore[d0], sXWn[s0] * sDinv[d0]);
    atomicAdd(&sScore[d1], sXWn[s1] * sDinv[d1]);
    atomicAdd(&sScore[d2], sXWn[s2] * sDinv[d2]);
    atomicAdd(&sScore[d3], sXWn[s3] * sDinv[d3]);
    atomicAdd(&sScore[d4], sXWn[s4] * sDinv[d4]);
    atomicAdd(&sScore[d5], sXWn[s5] * sDinv[d5]);
    atomicAdd(&sScore[d6], sXWn[s6] * sDinv[d6]);
    atomicAdd(&sScore[d7], sXWn[s7] * sDinv[d7]);
  }
  __syncthreads();                                      // B4

  // ---- P4: stable top-K rank (2 threads/node, b128 reads)
  {
    int node = tid & 255;
    int seg  = tid >> 8;
    float s_i = sScore[node];
    int base = seg * 32;
    int part = 0;
    #pragma unroll 8
    for (int t = 0; t < 32; ++t) {
      float4 v = sScore4[base + t];
      int jj = (base + t) * 4;
      part += (v.x > s_i) || (v.x == s_i && (jj + 0) < node);
      part += (v.y > s_i) || (v.y == s_i && (jj + 1) < node);
      part += (v.z > s_i) || (v.z == s_i && (jj + 2) < node);
      part += (v.w > s_i) || (v.w == s_i && (jj + 3) < node);
    }
    atomicAdd(&sRank[node], part);
  }
  __syncthreads();                                      // B5

  if (tid < NPER) {
    bool kp = sRank[tid] < KK;          // ranks are a permutation of 0..255
    float gate = tanhf(sScore[tid] + gcn_b[0]);
    sGF[tid] = make_float2(kp ? gate : 0.0f, kp ? 0.0f : INFINITY);
  }
  __syncthreads();                                      // B6

  // ---- P5: gated mean/max pool from registers (no global loads)
  float su0=0,su1=0,su2=0,su3=0,su4=0,su5=0,su6=0,su7=0;
  float mx0=-INFINITY,mx1=-INFINITY,mx2=-INFINITY,mx3=-INFINITY;
  float mx4=-INFINITY,mx5=-INFINITY,mx6=-INFINITY,mx7=-INFINITY;
  #pragma unroll
  for (int r = 0; r < 8; ++r) {
    float2 gf = sGF[r * 32 + wave * 4 + sub];   // 4 addr/wave, conflict-free broadcast
    float g1 = gf.x, fb = gf.y;
    float a;
    a = q0[r].x * g1; su0 += a; mx0 = fmaxf(mx0, a - fb);
    a = q0[r].y * g1; su1 += a; mx1 = fmaxf(mx1, a - fb);
    a = q0[r].z * g1; su2 += a; mx2 = fmaxf(mx2, a - fb);
    a = q0[r].w * g1; su3 += a; mx3 = fmaxf(mx3, a - fb);
    a = q1[r].x * g1; su4 += a; mx4 = fmaxf(mx4, a - fb);
    a = q1[r].y * g1; su5 += a; mx5 = fmaxf(mx5, a - fb);
    a = q1[r].z * g1; su6 += a; mx6 = fmaxf(mx6, a - fb);
    a = q1[r].w * g1; su7 += a; mx7 = fmaxf(mx7, a - fb);
  }
  // reduce over sub (lanes j, j^16, j^32, j^48)
  #define RED_S(v) v += __shfl_xor(v,16); v += __shfl_xor(v,32);
  #define RED_M(v) v = fmaxf(v,__shfl_xor(v,16)); v = fmaxf(v,__shfl_xor(v,32));
  RED_S(su0) RED_S(su1) RED_S(su2) RED_S(su3)
  RED_S(su4) RED_S(su5) RED_S(su6) RED_S(su7)
  RED_M(mx0) RED_M(mx1) RED_M(mx2) RED_M(mx3)
  RED_M(mx4) RED_M(mx5) RED_M(mx6) RED_M(mx7)
  if (sub == 0) {
    ((float4*)&sPoolS[wave][4 * j])[0]      = make_float4(su0, su1, su2, su3);
    ((float4*)&sPoolS[wave][64 + 4 * j])[0] = make_float4(su4, su5, su6, su7);
    ((float4*)&sPoolM[wave][4 * j])[0]      = make_float4(mx0, mx1, mx2, mx3);
    ((float4*)&sPoolM[wave][64 + 4 * j])[0] = make_float4(mx4, mx5, mx6, mx7);
  }
  __syncthreads();                                      // B7

  if (tid < DD) {                       // mean dims
    float s = 0.f;
    #pragma unroll
    for (int w = 0; w < NW; ++w) s += sPoolS[w][tid];
    sR[tid] = s * (1.0f / KK);
  } else if (tid < 2 * DD) {            // max dims
    int d = tid - DD;
    float m = -INFINITY;
    #pragma unroll
    for (int w = 0; w < NW; ++w) m = fmaxf(m, sPoolM[w][d]);
    sR[tid] = m;
  }
  __syncthreads();                                      // B8

  // ---- P6: out = [mean||max] @ lin_w + lin_b (lin_w L2-hot across 512 blocks)
  const float2* lw2 = (const float2*)lin_w;
  float a0 = 0.f, a1 = 0.f;
  #pragma unroll
  for (int t = 0; t < 16; ++t) {
    int k2 = wave * 16 + t;
    float2 rv = sR2[k2];                       // readout[2k2], readout[2k2+1]
    float2 p0 = lw2[(2 * k2) * 64 + lane];
    float2 p1 = lw2[(2 * k2 + 1) * 64 + lane];
    a0 += rv.x * p0.x + rv.y * p1.x;
    a1 += rv.x * p0.y + rv.y * p1.y;
  }
  float2* sP2 = (float2*)sPoolS;               // reuse as matvec partials
  sP2[wave * 64 + lane] = make_float2(a0, a1); // safe: all waves passed B8
  __syncthreads();                                      // B9
  if (wave == 0) {
    float2 a = sP2[lane];
    #pragma unroll
    for (int w = 1; w < NW; ++w) { float2 p = sP2[w * 64 + lane]; a.x += p.x; a.y += p.y; }
    float2 bb = ((const float2*)lin_b)[lane];
    a.x += bb.x; a.y += bb.y;
    ((float2*)out)[(size_t)g * 64 + lane] = a;
  }
}

extern "C" void kernel_launch(void* const* d_in, const int* in_sizes, int n_in,
                              void* d_out, int out_size, void* d_ws, size_t ws_size,
                              hipStream_t stream) {
  const float* x  = (const float*)d_in[0];
  // d_in[1] = graph_indicator (unused: equal-size contiguous graphs)
  const int*   ei = (const int*)d_in[2];
  const float* gw = (const float*)d_in[3];
  const float* gb = (const float*)d_in[4];
  const float* lw = (const float*)d_in[5];
  const float* lb = (const float*)d_in[6];
  float* out = (float*)d_out;
  const int E = in_sizes[2] / 2;       // edge_index is [2, E]
  sag_fused<<<NG, NT, 0, stream>>>(x, ei, ei + E, gw, gb, lw, lb, out);
}